// Round 7
// baseline (187.476 us; speedup 1.0000x reference)
//
#include <hip/hip_runtime.h>
#include <hip/hip_bf16.h>

#define N_IN    256
#define N_HID   128
#define N_ELEM  5
#define TILE    64                 // atoms per tile (natural order, contiguous)
#define F_ROWB  1040               // fp32 LDS row bytes (1024 + 16 pad)
#define B_ROWB  528                // bf16 LDS row bytes (512 + 16 pad)
#define NBLK    256                // persistent blocks, 1 per CU
#define CHUNK_MAX 13               // ceil(3125 / 256)

typedef __attribute__((ext_vector_type(8))) short  short8;
typedef __attribute__((ext_vector_type(4))) short  short4v;
typedef __attribute__((ext_vector_type(4))) float  float4v;

__device__ __forceinline__ int expert_of(int z) {
    return (z == 1) ? 0 : (z == 6) ? 1 : (z == 7) ? 2 : (z == 8) ? 3 : 4;
}
__device__ __forceinline__ short f2bf(float f) {
    union { float f; unsigned u; } c; c.f = f;
    unsigned r = (c.u + 0x7fffu + ((c.u >> 16) & 1u)) >> 16;
    return (short)r;
}

#define AS3 __attribute__((address_space(3)))
#define GLOAD_LDS16(gsrc, ldst) \
    __builtin_amdgcn_global_load_lds((const __attribute__((address_space(1))) void*)(gsrc), \
                                     (AS3 void*)(ldst), 16, 0, 0)
__device__ __forceinline__ unsigned lds_off(const void* p) {
    return (unsigned)(size_t)(AS3 const char*)p;
}

// inline-asm LDS ops — invisible to the waitcnt legalizer (no auto vmcnt drains)
#define DSR128(dst, a) asm volatile("ds_read_b128 %0, %1" : "=v"(dst) : "v"(a))
#define DSR32(dst, a)  asm volatile("ds_read_b32 %0, %1"  : "=v"(dst) : "v"(a))
#define DSW64(a, val)  asm volatile("ds_write_b64 %0, %1" :: "v"(a), "v"(val) : "memory")
#define DSW32(a, val)  asm volatile("ds_write_b32 %0, %1" :: "v"(a), "v"(val) : "memory")
#define SWIZ(dst, src, MASKSTR) \
    asm volatile("ds_swizzle_b32 %0, %1 offset:" MASKSTR : "=v"(dst) : "v"(src))
#define LGKM0 do { asm volatile("s_waitcnt lgkmcnt(0)" ::: "memory"); \
                   __builtin_amdgcn_sched_barrier(0); } while (0)
#define LGKM4 do { asm volatile("s_waitcnt lgkmcnt(4)" ::: "memory"); \
                   __builtin_amdgcn_sched_barrier(0); } while (0)
#define WAITV(n) do { asm volatile("s_waitcnt vmcnt(" #n ")" ::: "memory"); \
                      __builtin_amdgcn_sched_barrier(0); } while (0)
#define BAR() do { __builtin_amdgcn_s_barrier(); \
                   __builtin_amdgcn_sched_barrier(0); } while (0)

// ---------------- prep: W1 fp32 -> bf16 ---------------------------------------
__global__ void prep_w_kernel(const float* __restrict__ W1, short* __restrict__ W1b, int n) {
    int i = (blockIdx.x * blockDim.x + threadIdx.x) * 4;
    if (i >= n) return;
    float4v f = *(const float4v*)(W1 + i);
    short4v s;
    s[0] = f2bf(f[0]); s[1] = f2bf(f[1]); s[2] = f2bf(f[2]); s[3] = f2bf(f[3]);
    *(short4v*)(W1b + i) = s;
}

// ---------------- mlp: natural order, all-expert dense, epilogue select -------
// Persistent 1-block/CU (4 waves, 1/SIMD, 512-VGPR budget). Per tile:
//   WAITV(0); BAR; cvt fp32 LDS -> bf16 LDS (frees fp32 buf); BAR;
//   DMA-prefetch t+1 into fp32 buf (contiguous rows!); compute 5 experts from
//   bf16 LDS vs register-resident B (320 VGPR, all 5 experts); masked epilogue.
__launch_bounds__(256, 1)
__global__ void mlp_kernel(const float* __restrict__ X, const short* __restrict__ W1b,
                           const float* __restrict__ B1f, const float* __restrict__ W2f,
                           const float* __restrict__ B2f, const int* __restrict__ zz,
                           float* __restrict__ out, int nAtoms, int nT) {
    __shared__ char  Fs[TILE * F_ROWB];          // 66560 B (fp32 staging)
    __shared__ char  Bfs[TILE * B_ROWB];         // 33792 B (bf16 tile)
    __shared__ float part[TILE * 4];             // 1024 B
    __shared__ char  echunk[CHUNK_MAX * TILE];   // 832 B

    int tid  = threadIdx.x;
    int lane = tid & 63;
    int w    = tid >> 6;
    int am   = lane & 15, g = lane >> 4;

    int q = nT / NBLK, r = nT % NBLK;
    int b = blockIdx.x;
    int t0 = b * q + min(b, r);
    int t1 = t0 + q + (b < r ? 1 : 0);
    if (t0 >= t1) return;

    // ---- all 5 experts' B fragments + biases -> registers (once per block)
    short8 bfrag[N_ELEM][2][8];                  // 320 VGPR
    float  b1c[N_ELEM][2], w2c[N_ELEM][2], b2v[N_ELEM];
#pragma unroll
    for (int e = 0; e < N_ELEM; ++e) {
        const short* Wb = W1b + e * (N_HID * N_IN);
#pragma unroll
        for (int ni = 0; ni < 2; ++ni) {
            int c = w * 32 + ni * 16 + am;
#pragma unroll
            for (int kk = 0; kk < 8; ++kk)
                bfrag[e][ni][kk] = *(const short8*)(Wb + c * N_IN + kk * 32 + g * 8);
            b1c[e][ni] = B1f[e * N_HID + c];
            w2c[e][ni] = W2f[e * N_HID + c];
        }
        b2v[e] = B2f[e];
    }

    // ---- per-atom expert index for this block's chunk -> LDS bytes
    int nt = t1 - t0;
    for (int i = tid; i < nt * TILE; i += 256) {
        int a = t0 * TILE + i;
        echunk[i] = (char)expert_of(zz[min(a, nAtoms - 1)]);
    }
    asm volatile("" :: "r"(lds_off(echunk)) : "memory");   // keep stores live
    __syncthreads();                                        // clean baseline

    unsigned F_OFF = lds_off(Fs), B_OFF = lds_off(Bfs);
    unsigned P_OFF = lds_off(part), E_OFF = lds_off(echunk);

#define PREFETCH(t_) do {                                                       \
    int base_ = (t_) * TILE + w * 16;                                           \
    _Pragma("unroll")                                                           \
    for (int j_ = 0; j_ < 16; ++j_) {                                           \
        int a_ = min(base_ + j_, nAtoms - 1);                                   \
        GLOAD_LDS16(X + (size_t)a_ * N_IN + lane * 4, Fs + (w * 16 + j_) * F_ROWB); \
    } } while (0)

    PREFETCH(t0);

    for (int t = t0; t < t1; ++t) {
        int lt = t - t0;
        WAITV(0);                 // stragglers of prefetch(t) + old store — cheap
        BAR();

        // ---- cvt pass: fp32 tile -> bf16 tile (4 lanes per row)
        {
            int row = w * 16 + (lane >> 2), c4 = lane & 3;
#pragma unroll
            for (int s = 0; s < 16; ++s) {
                int ch = c4 + s * 4;
                float4v f = *(const float4v*)(Fs + row * F_ROWB + ch * 16);
                union { __hip_bfloat162 h[2]; long l; } o;
                o.h[0] = __float22bfloat162_rn({f[0], f[1]});
                o.h[1] = __float22bfloat162_rn({f[2], f[3]});
                DSW64(B_OFF - lds_off(Fs) + lds_off(Fs) + 0u +
                      (unsigned)(row * B_ROWB + ch * 8) + (B_OFF - B_OFF), o.l);
            }
        }
        LGKM0;
        BAR();                    // bf16 tile ready; fp32 buffer now free

        if (t + 1 < t1) PREFETCH(t + 1);   // overlaps all compute below

        // ---- per-atom expert masks (4 bytes per mi)
        unsigned emw[4];
#pragma unroll
        for (int mi = 0; mi < 4; ++mi) {
            unsigned ea = E_OFF + (unsigned)(lt * 64 + mi * 16 + g * 4);
            DSR32(emw[mi], ea);
        }

        // ---- compute: 5 experts sequentially, masked accumulate into pv
        float pv[4][4] = {};
#pragma unroll
        for (int e = 0; e < N_ELEM; ++e) {
            float4v acc[4][2] = {};
            short8 a8[2][4];
            unsigned ab = B_OFF + (unsigned)(am * B_ROWB + g * 16);
            DSR128(a8[0][0], ab);
            DSR128(a8[0][1], ab + 16 * B_ROWB);
            DSR128(a8[0][2], ab + 32 * B_ROWB);
            DSR128(a8[0][3], ab + 48 * B_ROWB);
#pragma unroll
            for (int kk = 0; kk < 8; ++kk) {
                if (kk < 7) {
                    unsigned o = ab + (kk + 1) * 64;
                    DSR128(a8[(kk + 1) & 1][0], o);
                    DSR128(a8[(kk + 1) & 1][1], o + 16 * B_ROWB);
                    DSR128(a8[(kk + 1) & 1][2], o + 32 * B_ROWB);
                    DSR128(a8[(kk + 1) & 1][3], o + 48 * B_ROWB);
                    LGKM4;
                } else {
                    LGKM0;
                }
#pragma unroll
                for (int mi = 0; mi < 4; ++mi) {
                    acc[mi][0] = __builtin_amdgcn_mfma_f32_16x16x32_bf16(
                        a8[kk & 1][mi], bfrag[e][0][kk], acc[mi][0], 0, 0, 0);
                    acc[mi][1] = __builtin_amdgcn_mfma_f32_16x16x32_bf16(
                        a8[kk & 1][mi], bfrag[e][1][kk], acc[mi][1], 0, 0, 0);
                }
            }
            // epilogue_e: bias + silu + dot(w2) + masked accumulate
#pragma unroll
            for (int mi = 0; mi < 4; ++mi)
#pragma unroll
                for (int rr = 0; rr < 4; ++rr) {
                    float s = 0.0f;
#pragma unroll
                    for (int ni = 0; ni < 2; ++ni) {
                        float v = acc[mi][ni][rr] + b1c[e][ni];
                        v = v / (1.0f + __expf(-v));
                        s += v * w2c[e][ni];
                    }
                    unsigned eb = (emw[mi] >> (rr * 8)) & 0xffu;
                    pv[mi][rr] += (eb == (unsigned)e) ? s : 0.0f;
                }
        }

        // ---- butterfly reduce over the 16 am-lanes
        {
            float tv[4][4];
#define RSTAGE(MASK)                                                            \
            _Pragma("unroll")                                                   \
            for (int mi = 0; mi < 4; ++mi) {                                    \
                SWIZ(tv[mi][0], pv[mi][0], MASK); SWIZ(tv[mi][1], pv[mi][1], MASK); \
                SWIZ(tv[mi][2], pv[mi][2], MASK); SWIZ(tv[mi][3], pv[mi][3], MASK); \
            }                                                                   \
            LGKM0;                                                              \
            _Pragma("unroll")                                                   \
            for (int mi = 0; mi < 4; ++mi) {                                    \
                pv[mi][0] += tv[mi][0]; pv[mi][1] += tv[mi][1];                 \
                pv[mi][2] += tv[mi][2]; pv[mi][3] += tv[mi][3];                 \
            }
            RSTAGE("0x041F") RSTAGE("0x081F") RSTAGE("0x101F") RSTAGE("0x201F")
#undef RSTAGE
        }

        // ---- cross-wave partial exchange + contiguous store
        if (am < 4) {
#pragma unroll
            for (int mi = 0; mi < 4; ++mi) {
                float val = (am == 0) ? pv[mi][0] : (am == 1) ? pv[mi][1]
                           : (am == 2) ? pv[mi][2] : pv[mi][3];
                unsigned pa = P_OFF + (unsigned)(((mi * 16 + g * 4 + am) * 4 + w) * 4);
                DSW32(pa, val);
            }
        }
        LGKM0;
        BAR();
        {
            float4v s4;
            DSR128(s4, P_OFF + (unsigned)((w * 16 + am) * 16));
            unsigned ew;
            DSR32(ew, E_OFF + (unsigned)(lt * 64 + w * 16 + (am & ~3)));
            LGKM0;
            unsigned eb = (ew >> ((am & 3) * 8)) & 0xffu;
            float bb = (eb == 0) ? b2v[0] : (eb == 1) ? b2v[1] : (eb == 2) ? b2v[2]
                     : (eb == 3) ? b2v[3] : b2v[4];
            int a_store = t * TILE + w * 16 + am;
            if (g == 0 && a_store < nAtoms)
                out[a_store] = s4[0] + s4[1] + s4[2] + s4[3] + bb;
        }
    }
#undef PREFETCH
}

// ---------------- launch -------------------------------------------------------
extern "C" void kernel_launch(void* const* d_in, const int* in_sizes, int n_in,
                              void* d_out, int out_size, void* d_ws, size_t ws_size,
                              hipStream_t stream) {
    const int*   z  = (const int*)  d_in[0];
    const float* X  = (const float*)d_in[1];
    const float* W1 = (const float*)d_in[2];
    const float* B1 = (const float*)d_in[3];
    const float* W2 = (const float*)d_in[4];
    const float* B2 = (const float*)d_in[5];
    float* out = (float*)d_out;
    int nAtoms = in_sizes[0];

    short* W1b = (short*)d_ws;                 // 327,680 B in workspace

    int wElems = N_ELEM * N_HID * N_IN;        // 163840
    prep_w_kernel<<<(wElems / 4 + 255) / 256, 256, 0, stream>>>(W1, W1b, wElems);

    int nT = (nAtoms + TILE - 1) / TILE;       // 3125
    mlp_kernel<<<NBLK, 256, 0, stream>>>(X, W1b, B1, W2, B2, z, out, nAtoms, nT);
}

// Round 8
// 119.728 us; speedup vs baseline: 1.5659x; 1.5659x over previous
//
#include <hip/hip_runtime.h>
#include <hip/hip_bf16.h>

#define N_IN    256
#define N_HID   128
#define N_ELEM  5
#define BM      128                // atoms per block (natural order, contiguous)
#define MAXT    12                 // max 16-row tiles: 5 + floor(123/16) = 12
#define MAXSLOT 192                // max padded slots: 16 * MAXT

typedef __attribute__((ext_vector_type(8))) short  short8;
typedef __attribute__((ext_vector_type(4))) short  short4v;
typedef __attribute__((ext_vector_type(4))) float  float4v;

__device__ __forceinline__ int expert_of(int z) {
    // 1->0 (H), 6->1 (C), 7->2 (N), 8->3 (O), 16->4 (S)
    return (z == 1) ? 0 : (z == 6) ? 1 : (z == 7) ? 2 : (z == 8) ? 3 : 4;
}
__device__ __forceinline__ short f2bf(float f) {
    union { float f; unsigned u; } c; c.f = f;
    unsigned r = (c.u + 0x7fffu + ((c.u >> 16) & 1u)) >> 16;
    return (short)r;
}

// ---------------- prep: W1 fp32 -> bf16 ---------------------------------------
__global__ void prep_w_kernel(const float* __restrict__ W1, short* __restrict__ W1b, int n) {
    int i = (blockIdx.x * blockDim.x + threadIdx.x) * 4;
    if (i >= n) return;
    float4v f = *(const float4v*)(W1 + i);
    short4v s;
    s[0] = f2bf(f[0]); s[1] = f2bf(f[1]); s[2] = f2bf(f[2]); s[3] = f2bf(f[3]);
    *(short4v*)(W1b + i) = s;
}

// ---------------- mlp: contiguous load + local expert bucketing ----------------
// Per block of 128 atoms (natural order):
//  1. bucket atoms by expert in LDS (counts -> prefix -> rowmap), build tile list
//  2. reg-stage X fp32 -> bf16 LDS tile (contiguous, coalesced, XOR-16 swizzle)
//  3. per 16-row tile: all 4 waves compute their 32-hidden slice vs register-
//     resident B (reloaded from L2 only on expert change, <=5x/block),
//     silu+dot in regs, butterfly over am-lanes, cross-wave sum in LDS, store.
__launch_bounds__(256, 2)
__global__ void mlp_kernel(const float* __restrict__ X, const short* __restrict__ W1b,
                           const float* __restrict__ B1f, const float* __restrict__ W2f,
                           const float* __restrict__ B2f, const int* __restrict__ zz,
                           float* __restrict__ out, int nAtoms) {
    __shared__ char  Xb[BM * 512];          // 65536 B bf16 tile, XOR-16 swizzled
    __shared__ int   rowmap[MAXSLOT];       // slot -> local row
    __shared__ float partb[2][4][16];       // [pingpong][wave][row]
    __shared__ int   cnt[N_ELEM], pfx[N_ELEM];
    __shared__ int   tend16[MAXT];          // per-tile absolute slot end
    __shared__ unsigned char texp_s[MAXT];
    __shared__ short tslot_s[MAXT];
    __shared__ int   nT_s;

    int tid  = threadIdx.x;
    int lane = tid & 63;
    int w    = tid >> 6;
    int am   = lane & 15, g = lane >> 4;

    int base = blockIdx.x * BM;
    int nLoc = min(BM, nAtoms - base);

    // ---- 1. bucket ------------------------------------------------------------
    if (tid < N_ELEM) cnt[tid] = 0;
    for (int i = tid; i < MAXSLOT; i += 256) rowmap[i] = 0;
    __syncthreads();
    int my_e = -1, my_r = 0;
    if (tid < nLoc) {
        my_e = expert_of(zz[base + tid]);
        my_r = atomicAdd(&cnt[my_e], 1);
    }
    __syncthreads();
    if (tid == 0) {
        int off = 0, t = 0;
        for (int e = 0; e < N_ELEM; ++e) {
            int c = cnt[e];
            pfx[e] = off;
            int ne = (c + 15) >> 4;
            for (int j = 0; j < ne; ++j) {
                texp_s[t] = (unsigned char)e;
                tslot_s[t] = (short)(off + j * 16);
                tend16[t] = off + c;
                ++t;
            }
            off += c;
        }
        nT_s = t;
    }
    __syncthreads();
    if (my_e >= 0) rowmap[pfx[my_e] + my_r] = tid;

    // ---- 2. stage X: fp32 global (contiguous) -> bf16 LDS (swizzled) ----------
    // flat float4 index f4 = c*256+tid: wave reads 1KB contiguous per instr.
    {
        const float* Xp = X + (size_t)base * N_IN;
        int nc = nLoc - 1;
#pragma unroll
        for (int cb = 0; cb < 4; ++cb) {
            float4v v[8];
#pragma unroll
            for (int u = 0; u < 8; ++u) {
                int f4 = (cb * 8 + u) * 256 + tid;
                int row = f4 >> 6, col = f4 & 63;
                int rc = min(row, nc);
                v[u] = *(const float4v*)(Xp + (size_t)rc * N_IN + col * 4);
            }
#pragma unroll
            for (int u = 0; u < 8; ++u) {
                int f4 = (cb * 8 + u) * 256 + tid;
                int row = f4 >> 6, col = f4 & 63;
                union { __hip_bfloat162 h[2]; unsigned long long l; } o;
                o.h[0] = __float22bfloat162_rn({v[u][0], v[u][1]});
                o.h[1] = __float22bfloat162_rn({v[u][2], v[u][3]});
                unsigned off = (unsigned)(row * 512 + ((col * 8) ^ ((row & 7) << 4)));
                *(unsigned long long*)(Xb + off) = o.l;
            }
        }
    }
    __syncthreads();        // rowmap + tiles + bf16 tile all ready

    // ---- 3. compute tiles ------------------------------------------------------
    int ecur = -1;
    short8 bfrag[2][8];                    // 64 VGPR: one expert, 32 hidden cols
    float b1c[2], w2c[2], b2v = 0.0f;
    int nT = nT_s;

    for (int t = 0; t < nT; ++t) {
        int e = texp_s[t];
        if (e != ecur) {
            ecur = e;
            const short* Wb = W1b + e * (N_HID * N_IN);
#pragma unroll
            for (int ni = 0; ni < 2; ++ni) {
                int c = w * 32 + ni * 16 + am;
#pragma unroll
                for (int kk = 0; kk < 8; ++kk)
                    bfrag[ni][kk] = *(const short8*)(Wb + c * N_IN + kk * 32 + g * 8);
                b1c[ni] = B1f[e * N_HID + c];
                w2c[ni] = W2f[e * N_HID + c];
            }
            b2v = B2f[e];
        }

        int slotb = tslot_s[t];
        int row = rowmap[slotb + am];
        unsigned rbase = (unsigned)(row * 512);
        unsigned rx = (unsigned)((row & 7) << 4);

        float4v acc0 = {}, acc1 = {};
#pragma unroll
        for (int kk = 0; kk < 8; ++kk) {
            short8 a = *(const short8*)(Xb + (rbase + (unsigned)((kk * 64 + g * 16) ^ rx)));
            acc0 = __builtin_amdgcn_mfma_f32_16x16x32_bf16(a, bfrag[0][kk], acc0, 0, 0, 0);
            acc1 = __builtin_amdgcn_mfma_f32_16x16x32_bf16(a, bfrag[1][kk], acc1, 0, 0, 0);
        }

        // bias + silu + layer-2 dot (per-lane 32-hidden slice)
        float pv0, pv1, pv2, pv3;
        {
            float v0 = acc0[0] + b1c[0]; v0 = v0 / (1.0f + __expf(-v0));
            float u0 = acc1[0] + b1c[1]; u0 = u0 / (1.0f + __expf(-u0));
            pv0 = v0 * w2c[0] + u0 * w2c[1];
            float v1 = acc0[1] + b1c[0]; v1 = v1 / (1.0f + __expf(-v1));
            float u1 = acc1[1] + b1c[1]; u1 = u1 / (1.0f + __expf(-u1));
            pv1 = v1 * w2c[0] + u1 * w2c[1];
            float v2 = acc0[2] + b1c[0]; v2 = v2 / (1.0f + __expf(-v2));
            float u2 = acc1[2] + b1c[1]; u2 = u2 / (1.0f + __expf(-u2));
            pv2 = v2 * w2c[0] + u2 * w2c[1];
            float v3 = acc0[3] + b1c[0]; v3 = v3 / (1.0f + __expf(-v3));
            float u3 = acc1[3] + b1c[1]; u3 = u3 / (1.0f + __expf(-u3));
            pv3 = v3 * w2c[0] + u3 * w2c[1];
        }
        // butterfly over the 16 am-lanes (hidden dimension)
#pragma unroll
        for (int s = 1; s <= 8; s <<= 1) {
            pv0 += __shfl_xor(pv0, s, 64);
            pv1 += __shfl_xor(pv1, s, 64);
            pv2 += __shfl_xor(pv2, s, 64);
            pv3 += __shfl_xor(pv3, s, 64);
        }
        if (am == 0) {                     // lanes 0,16,32,48: rows g*4..g*4+3
            float4v p4 = {pv0, pv1, pv2, pv3};
            *(float4v*)&partb[t & 1][w][g * 4] = p4;
        }
        __syncthreads();
        if (tid < 16) {
            float y = partb[t & 1][0][tid] + partb[t & 1][1][tid]
                    + partb[t & 1][2][tid] + partb[t & 1][3][tid] + b2v;
            int slot = slotb + tid;
            if (slot < tend16[t]) out[base + rowmap[slot]] = y;
        }
    }
}

// ---------------- launch -------------------------------------------------------
extern "C" void kernel_launch(void* const* d_in, const int* in_sizes, int n_in,
                              void* d_out, int out_size, void* d_ws, size_t ws_size,
                              hipStream_t stream) {
    const int*   z  = (const int*)  d_in[0];
    const float* X  = (const float*)d_in[1];
    const float* W1 = (const float*)d_in[2];
    const float* B1 = (const float*)d_in[3];
    const float* W2 = (const float*)d_in[4];
    const float* B2 = (const float*)d_in[5];
    float* out = (float*)d_out;
    int nAtoms = in_sizes[0];

    short* W1b = (short*)d_ws;                 // 327,680 B in workspace

    int wElems = N_ELEM * N_HID * N_IN;        // 163840
    prep_w_kernel<<<(wElems / 4 + 255) / 256, 256, 0, stream>>>(W1, W1b, wElems);

    int nBlocks = (nAtoms + BM - 1) / BM;      // 1563
    mlp_kernel<<<nBlocks, 256, 0, stream>>>(X, W1b, B1, W2, B2, z, out, nAtoms);
}

// Round 9
// 80.848 us; speedup vs baseline: 2.3189x; 1.4809x over previous
//
#include <hip/hip_runtime.h>
#include <hip/hip_bf16.h>

#define N_IN    256
#define N_HID   128
#define N_ELEM  5
#define NBLK    256                 // persistent blocks, 1 per CU
#define TMAX    14                  // max 64-row tiles per block
#define ESTRIDE 66560               // per-expert image: 65536 frag + 1024 params

typedef __attribute__((ext_vector_type(8))) short  short8;
typedef __attribute__((ext_vector_type(4))) short  short4v;
typedef __attribute__((ext_vector_type(4))) float  float4v;

__device__ __forceinline__ int expert_of(int z) {
    return (z == 1) ? 0 : (z == 6) ? 1 : (z == 7) ? 2 : (z == 8) ? 3 : 4;
}
__device__ __forceinline__ short f2bf(float f) {
    union { float f; unsigned u; } c; c.f = f;
    unsigned r = (c.u + 0x7fffu + ((c.u >> 16) & 1u)) >> 16;
    return (short)r;
}

#define AS3 __attribute__((address_space(3)))
#define GLOAD_LDS16(gsrc, ldst) \
    __builtin_amdgcn_global_load_lds((const __attribute__((address_space(1))) void*)(gsrc), \
                                     (AS3 void*)(ldst), 16, 0, 0)
__device__ __forceinline__ unsigned lds_off(const void* p) {
    return (unsigned)(size_t)(AS3 const char*)p;
}

#define DSR128(dst, a) asm volatile("ds_read_b128 %0, %1" : "=v"(dst) : "v"(a))
#define DSR32(dst, a)  asm volatile("ds_read_b32 %0, %1"  : "=v"(dst) : "v"(a))
#define DSW32(a, val)  asm volatile("ds_write_b32 %0, %1" :: "v"(a), "v"(val) : "memory")
#define LGKM0 do { asm volatile("s_waitcnt lgkmcnt(0)" ::: "memory"); \
                   __builtin_amdgcn_sched_barrier(0); } while (0)
#define WAITV(n) do { asm volatile("s_waitcnt vmcnt(" #n ")" ::: "memory"); \
                      __builtin_amdgcn_sched_barrier(0); } while (0)
#define BAR() do { __builtin_amdgcn_s_barrier(); \
                   __builtin_amdgcn_sched_barrier(0); } while (0)

// ---------------- fused prep (swizzled W1 frag image + params) + histogram ----
__global__ void prep_hist_kernel(const float* __restrict__ W1, const float* __restrict__ B1f,
                                 const float* __restrict__ W2f, char* __restrict__ W1s,
                                 const int* __restrict__ z, int n, int* __restrict__ counts) {
    if (blockIdx.x < 85) {
        int idx = blockIdx.x * 256 + threadIdx.x;
        if (idx < 20480) {                       // frag path: one 16B frag per thread
            int e = idx >> 12, rem = idx & 4095;
            int slot = rem >> 6, lane = rem & 63;
            int nrow = (slot >> 3) * 16 + (lane & 15);
            int k0 = (slot & 7) * 32 + (lane >> 4) * 8;
            const float* src = W1 + ((size_t)(e * N_HID + nrow) * N_IN + k0);
            float4v f0 = *(const float4v*)src;
            float4v f1 = *(const float4v*)(src + 4);
            short8 s;
            s[0] = f2bf(f0[0]); s[1] = f2bf(f0[1]); s[2] = f2bf(f0[2]); s[3] = f2bf(f0[3]);
            s[4] = f2bf(f1[0]); s[5] = f2bf(f1[1]); s[6] = f2bf(f1[2]); s[7] = f2bf(f1[3]);
            *(short8*)(W1s + (size_t)e * ESTRIDE + slot * 1024 + lane * 16) = s;
        } else {                                 // params: b1[128] fp32, w2[128] fp32
            int idx2 = idx - 20480;              // < 1280
            int e = idx2 >> 8, i = idx2 & 255;
            float* dst = (float*)(W1s + (size_t)e * ESTRIDE + 65536);
            if (i < 128) dst[i] = B1f[e * N_HID + i];
            else         dst[128 + (i - 128)] = W2f[e * N_HID + (i - 128)];
        }
        return;
    }
    __shared__ int cnt[N_ELEM];
    if (threadIdx.x < N_ELEM) cnt[threadIdx.x] = 0;
    __syncthreads();
    int i = (blockIdx.x - 85) * blockDim.x + threadIdx.x;
    if (i < n) atomicAdd(&cnt[expert_of(z[i])], 1);
    __syncthreads();
    if (threadIdx.x < N_ELEM && cnt[threadIdx.x]) atomicAdd(&counts[threadIdx.x], cnt[threadIdx.x]);
}

// ---------------- meta + scatter ----------------------------------------------
__global__ void build_meta_kernel(const int* __restrict__ counts, int* __restrict__ cursor,
                                  int* __restrict__ meta) {
    if (threadIdx.x == 0) {
        int o = 0, tp = 0;
        for (int e = 0; e < N_ELEM; ++e) {
            int c = counts[e];
            meta[e] = o; meta[5 + e] = c; meta[10 + e] = tp;
            cursor[e] = o;
            o += c; tp += (c + 63) >> 6;
        }
        meta[15] = tp;
    }
}

__global__ void scatter_kernel(const int* __restrict__ z, int n,
                               int* __restrict__ cursor, int* __restrict__ perm) {
    __shared__ int cnt[N_ELEM], cur[N_ELEM], base[N_ELEM];
    int tid = threadIdx.x;
    if (tid < N_ELEM) { cnt[tid] = 0; cur[tid] = 0; }
    __syncthreads();
    int i = blockIdx.x * blockDim.x + tid;
    int e = -1;
    if (i < n) { e = expert_of(z[i]); atomicAdd(&cnt[e], 1); }
    __syncthreads();
    if (tid < N_ELEM) base[tid] = cnt[tid] ? atomicAdd(&cursor[tid], cnt[tid]) : 0;
    __syncthreads();
    if (e >= 0) {
        int r = atomicAdd(&cur[e], 1);
        perm[base[e] + r] = i;
    }
}

// ---------------- mlp: persistent 8-wave blocks, B-in-LDS, ring-4 A chunks ----
__launch_bounds__(512, 1)
__global__ void mlp_kernel(const float* __restrict__ X, const char* __restrict__ W1s,
                           const float* __restrict__ B2f, const int* __restrict__ perm,
                           const int* __restrict__ meta, float* __restrict__ out) {
    __shared__ char  As[4 * 16384];          // ring-4 A chunks (fp32, src-swizzled)
    __shared__ char  Bs[ESTRIDE];            // one expert: frags + params
    __shared__ int   gidT[TMAX * 64];
    __shared__ float part[2 * 2 * 64];

    int tid  = threadIdx.x;
    int lane = tid & 63;
    int w    = tid >> 6;                     // 8 waves
    int am   = lane & 15, g = lane >> 4;
    int mq   = w >> 1, nh = w & 1;           // rows mq*16.., hidden nh*64..

    int so0 = meta[0], so1 = meta[1], so2 = meta[2], so3 = meta[3], so4 = meta[4];
    int ct0 = meta[5], ct1 = meta[6], ct2 = meta[7], ct3 = meta[8], ct4 = meta[9];
    int tp1 = meta[11], tp2 = meta[12], tp3 = meta[13], tp4 = meta[14];
    int nSub = meta[15];

    int q = nSub / NBLK, r = nSub % NBLK;
    int b = blockIdx.x;
    int t0 = b * q + min(b, r);
    int t1 = t0 + q + (b < r ? 1 : 0);
    if (t0 >= t1) return;

    for (int i = tid; i < (t1 - t0) * 64; i += 512) {
        int tl = t0 + (i >> 6);
        int e = (tl >= tp1) + (tl >= tp2) + (tl >= tp3) + (tl >= tp4);
        int so = so0, ct = ct0, tb = 0;
        if (e == 1) { so = so1; ct = ct1; tb = tp1; }
        else if (e == 2) { so = so2; ct = ct2; tb = tp2; }
        else if (e == 3) { so = so3; ct = ct3; tb = tp3; }
        else if (e == 4) { so = so4; ct = ct4; tb = tp4; }
        int rs = so + (tl - tb) * 64;
        gidT[i] = perm[min(rs + (i & 63), so + ct - 1)];
    }
    __syncthreads();

    unsigned A_OFF = lds_off(As), B_OFF = lds_off(Bs);
    unsigned GID_OFF = lds_off(gidT), PART_OFF = lds_off(part);
    unsigned PRM_OFF = B_OFF + 65536u;

#define ISSUE_A(cg_) do {                                                        \
    int tl_ = tRunL + ((cg_) >> 2);                                              \
    unsigned c_ = (unsigned)((cg_) & 3);                                         \
    unsigned ga_ = GID_OFF + (unsigned)((tl_ * 64 + w * 8 + (lane >> 4)) * 4);   \
    unsigned gA_, gB_;                                                           \
    DSR32(gA_, ga_); DSR32(gB_, ga_ + 16);                                       \
    LGKM0;                                                                       \
    {                                                                            \
        unsigned sl_ = (unsigned)(lane & 15);                                    \
        unsigned rA_ = (unsigned)(w * 8) + (unsigned)(lane >> 4);                \
        unsigned rB_ = rA_ + 4u;                                                 \
        const float* sA_ = X + ((size_t)gA_ << 8) + (c_ << 6) + ((sl_ ^ (rA_ & 7u)) << 2); \
        const float* sB_ = X + ((size_t)gB_ << 8) + (c_ << 6) + ((sl_ ^ (rB_ & 7u)) << 2); \
        GLOAD_LDS16(sA_, As + (((unsigned)(cg_) & 3u) << 14) + w * 2048);        \
        GLOAD_LDS16(sB_, As + (((unsigned)(cg_) & 3u) << 14) + w * 2048 + 1024); \
    } } while (0)

#define COMPUTE_CHUNK(cg_) do {                                                  \
    int c_ = (cg_) & 3;                                                          \
    unsigned ring_ = A_OFF + (((unsigned)(cg_) & 3u) << 14);                     \
    unsigned row_ = (unsigned)(mq * 16 + am);                                    \
    unsigned rbase_ = ring_ + (row_ << 8);                                       \
    unsigned rx_ = row_ & 7u;                                                    \
    _Pragma("unroll")                                                            \
    for (int klo_ = 0; klo_ < 2; ++klo_) {                                       \
        unsigned s0_ = (unsigned)(klo_ * 8 + g * 2);                             \
        float4v f0_, f1_;                                                        \
        DSR128(f0_, rbase_ + ((s0_ ^ rx_) << 4));                                \
        DSR128(f1_, rbase_ + (((s0_ + 1u) ^ rx_) << 4));                         \
        int kk_ = c_ * 2 + klo_;                                                 \
        unsigned bb_ = B_OFF + (unsigned)((((nh * 4) * 8 + kk_) * 64 + lane) * 16); \
        short8 b0_, b1_, b2_, b3_;                                               \
        DSR128(b0_, bb_);                                                        \
        DSR128(b1_, bb_ + 8192u);                                                \
        DSR128(b2_, bb_ + 16384u);                                               \
        DSR128(b3_, bb_ + 24576u);                                               \
        LGKM0;                                                                   \
        union { __hip_bfloat162 h[4]; short8 s; } a_;                            \
        a_.h[0] = __float22bfloat162_rn({f0_[0], f0_[1]});                       \
        a_.h[1] = __float22bfloat162_rn({f0_[2], f0_[3]});                       \
        a_.h[2] = __float22bfloat162_rn({f1_[0], f1_[1]});                       \
        a_.h[3] = __float22bfloat162_rn({f1_[2], f1_[3]});                       \
        acc[0] = __builtin_amdgcn_mfma_f32_16x16x32_bf16(a_.s, b0_, acc[0], 0, 0, 0); \
        acc[1] = __builtin_amdgcn_mfma_f32_16x16x32_bf16(a_.s, b1_, acc[1], 0, 0, 0); \
        acc[2] = __builtin_amdgcn_mfma_f32_16x16x32_bf16(a_.s, b2_, acc[2], 0, 0, 0); \
        acc[3] = __builtin_amdgcn_mfma_f32_16x16x32_bf16(a_.s, b3_, acc[3], 0, 0, 0); \
    } } while (0)

#define EPILOGUE(tl_, pp_) do {                                                  \
    float pvv_[4];                                                               \
    _Pragma("unroll")                                                            \
    for (int rr_ = 0; rr_ < 4; ++rr_) {                                          \
        float s_ = 0.0f;                                                         \
        _Pragma("unroll")                                                        \
        for (int ni_ = 0; ni_ < 4; ++ni_) {                                      \
            float v_ = acc[ni_][rr_] + b1c[ni_];                                 \
            v_ = v_ / (1.0f + __expf(-v_));                                      \
            s_ += v_ * w2c[ni_];                                                 \
        }                                                                        \
        pvv_[rr_] = s_;                                                          \
    }                                                                            \
    _Pragma("unroll")                                                            \
    for (int sh_ = 1; sh_ <= 8; sh_ <<= 1) {                                     \
        pvv_[0] += __shfl_xor(pvv_[0], sh_, 64);                                 \
        pvv_[1] += __shfl_xor(pvv_[1], sh_, 64);                                 \
        pvv_[2] += __shfl_xor(pvv_[2], sh_, 64);                                 \
        pvv_[3] += __shfl_xor(pvv_[3], sh_, 64);                                 \
    }                                                                            \
    if (am < 4) {                                                                \
        float val_ = (am == 0) ? pvv_[0] : (am == 1) ? pvv_[1]                   \
                   : (am == 2) ? pvv_[2] : pvv_[3];                              \
        unsigned pa_ = PART_OFF + (unsigned)((pp_) * 512 + nh * 256              \
                     + (mq * 16 + g * 4 + am) * 4);                              \
        DSW32(pa_, val_);                                                        \
    }                                                                            \
    LGKM0; BAR();                                                                \
    if (w == 0) {                                                                \
        float p0_, p1_; unsigned gi_;                                            \
        unsigned pb_ = PART_OFF + (unsigned)((pp_) * 512 + lane * 4);            \
        DSR32(p0_, pb_); DSR32(p1_, pb_ + 256u);                                 \
        DSR32(gi_, GID_OFF + (unsigned)(((tl_) * 64 + lane) * 4));               \
        LGKM0;                                                                   \
        out[gi_] = p0_ + p1_ + b2v;                                              \
    } } while (0)

    int t = t0;
    while (t < t1) {
        int e = (t >= tp1) + (t >= tp2) + (t >= tp3) + (t >= tp4);
        int te = (e == 0) ? tp1 : (e == 1) ? tp2 : (e == 2) ? tp3 : (e == 3) ? tp4 : nSub;
        int runEnd = min(t1, te);
        int tRunL = t - t0;
        int C = (runEnd - t) * 4;

        WAITV(0); BAR();
        float b2v;
        {
            const float* bp = B2f + e;
            asm volatile("global_load_dword %0, %1, off" : "=v"(b2v) : "v"(bp));
        }
        {
            const char* We = W1s + (size_t)e * ESTRIDE;
            for (int i = w; i < 65; i += 8)
                GLOAD_LDS16(We + i * 1024 + lane * 16, Bs + i * 1024);
        }
        ISSUE_A(0); ISSUE_A(1); ISSUE_A(2);

        float b1c[4], w2c[4];
        float4v acc[4];
        for (int cg = 0; cg < C; ++cg) {
            if (cg + 3 <= C - 1)      WAITV(4);
            else if (cg + 2 <= C - 1) WAITV(2);
            else                      WAITV(0);
            BAR();
            if (cg == 0) {
#pragma unroll
                for (int ni = 0; ni < 4; ++ni) {
                    unsigned col = (unsigned)(((nh * 4 + ni) * 16 + am) * 4);
                    DSR32(b1c[ni], PRM_OFF + col);
                    DSR32(w2c[ni], PRM_OFF + 512u + col);
                }
                LGKM0;
            }
            if (cg + 3 < C) ISSUE_A(cg + 3);
            if ((cg & 3) == 0) {
                acc[0] = (float4v){0,0,0,0}; acc[1] = (float4v){0,0,0,0};
                acc[2] = (float4v){0,0,0,0}; acc[3] = (float4v){0,0,0,0};
            }
            COMPUTE_CHUNK(cg);
            if ((cg & 3) == 3) EPILOGUE(tRunL + (cg >> 2), (cg >> 2) & 1);
        }
        t = runEnd;
    }
#undef ISSUE_A
#undef COMPUTE_CHUNK
#undef EPILOGUE
}

// ---------------- launch -------------------------------------------------------
extern "C" void kernel_launch(void* const* d_in, const int* in_sizes, int n_in,
                              void* d_out, int out_size, void* d_ws, size_t ws_size,
                              hipStream_t stream) {
    const int*   z  = (const int*)  d_in[0];
    const float* X  = (const float*)d_in[1];
    const float* W1 = (const float*)d_in[2];
    const float* B1 = (const float*)d_in[3];
    const float* W2 = (const float*)d_in[4];
    const float* B2 = (const float*)d_in[5];
    float* out = (float*)d_out;
    int nAtoms = in_sizes[0];

    char* ws = (char*)d_ws;
    size_t off = 0;
    char* W1s   = ws + off;           off += (size_t)N_ELEM * ESTRIDE;   // 332800
    int* perm   = (int*)(ws + off);   off += (size_t)nAtoms * 4;
    int* counts = (int*)(ws + off);   off += 32;
    int* cursor = (int*)(ws + off);   off += 32;
    int* meta   = (int*)(ws + off);   off += 64;

    hipMemsetAsync(counts, 0, 32, stream);

    int hb = (nAtoms + 255) / 256;
    prep_hist_kernel<<<85 + hb, 256, 0, stream>>>(W1, B1, W2, W1s, z, nAtoms, counts);
    build_meta_kernel<<<1, 64, 0, stream>>>(counts, cursor, meta);
    scatter_kernel<<<hb, 256, 0, stream>>>(z, nAtoms, cursor, perm);
    mlp_kernel<<<NBLK, 512, 0, stream>>>(X, W1s, B2, perm, meta, out);
}